// Round 1
// 103.989 us; speedup vs baseline: 1.0363x; 1.0363x over previous
//
#include <hip/hip_runtime.h>
#include <hip/hip_fp16.h>
#include <math.h>

#define OBJ_D 320
#define LANG_D 256
#define GEO_D 6
#define HID 256
#define NN 512
#define BATCH 2

// gelu(a) ~= 0.5a + GK0*a^2 + GK1*a^4,  GK1 = -GK0/6 (same poly as prior kernel).
// Factorized: score = Ci + Dj + 2*GK0*sum_h (W2*x_i)*v_j  (quartic cross terms ~1e-8, dropped)
#define GK0 0.3989422804014327f
#define GK1 (-0.066490380066905448f)
#define SCA (512.0f * GK0)        /* = 256 * 2*GK0 : f16 A-operand scale      */
#define INV_SCA (1.0f / 256.0f)   /* undo after fp32 MFMA accumulation        */

typedef _Float16 v8h __attribute__((ext_vector_type(8)));
typedef float f32x4 __attribute__((ext_vector_type(4)));

__device__ __forceinline__ float wave_allreduce_sum(float v) {
#pragma unroll
    for (int o = 32; o > 0; o >>= 1) v += __shfl_xor(v, o, 64);
    return v;
}

// k_pre: blocks 0..255 = fused l2norm + dual matmul (fp32, exact) producing
//   hi_p (fp32 [b][i][h]), Bj_h (f16 row-major [b][j][h]  — GEMM B^T operand),
//   embT2 (f16 j-pairs, [b][d][jp] — transposed emb for context GEMM B operand),
//   DjT (fp32 exact per-j score part: sum_h W2*(0.5v + GK0 v^2 + GK1 v^4)).
// blocks 256..257 = lang norm + hl (b1 folded in).
__global__ __launch_bounds__(256) void k_pre(const float* __restrict__ emb,
                                             const float* __restrict__ geom,
                                             const float* __restrict__ utter,
                                             const float* __restrict__ W1,
                                             const float* __restrict__ b1,
                                             const float* __restrict__ W2,
                                             __half2* __restrict__ embT2,
                                             float* __restrict__ hi_p,
                                             _Float16* __restrict__ Bj_h,
                                             float* __restrict__ hl,
                                             float* __restrict__ DjT) {
    int tid = threadIdx.x;
    int wid = tid >> 6, lane = tid & 63;

    __shared__ float4 esT4[OBJ_D];
    __shared__ float gs[4][GEO_D];
    __shared__ float rn[4];
    __shared__ float lang_s[LANG_D];
    __shared__ float red[8];
    __shared__ float redD[4][4];
    float* esT = (float*)esT4;

    if (blockIdx.x >= 256) {
        int lb = blockIdx.x - 256;
        float v = utter[lb * LANG_D + tid];
        float ss = wave_allreduce_sum(v * v);
        if (lane == 0) red[wid] = ss;
        __syncthreads();
        if (tid == 0) red[0] = 1.0f / fmaxf(sqrtf(red[0] + red[1] + red[2] + red[3]), 1e-12f);
        __syncthreads();
        lang_s[tid] = v * red[0];
        __syncthreads();
        const float* Wl = W1 + (size_t)(2 * OBJ_D + GEO_D) * HID + tid;
        float acc = b1[tid];
#pragma unroll 8
        for (int l2 = 0; l2 < LANG_D; l2++) acc = fmaf(lang_s[l2], Wl[(size_t)l2 * HID], acc);
        hl[lb * HID + tid] = acc;
        return;
    }

    const int R = 4;
    int b = blockIdx.x & 1;
    int n0 = (blockIdx.x >> 1) * R;

    const float* WiC = W1 + tid;
    const float* WjC = W1 + (size_t)OBJ_D * HID + tid;
    float wi[16], wj[16], win[16], wjn[16];
#pragma unroll
    for (int k = 0; k < 16; k++) {
        wi[k] = WiC[(size_t)k * HID];
        wj[k] = WjC[(size_t)k * HID];
    }

    const float* esrc = emb + (size_t)(b * NN + n0) * OBJ_D;
    float ev[5]; int er[5], ed[5];
#pragma unroll
    for (int k = 0; k < 5; k++) {
        int idx = k * 256 + tid;
        ev[k] = esrc[idx];
        er[k] = idx / OBJ_D; ed[k] = idx % OBJ_D;
        esT[ed[k] * 4 + er[k]] = ev[k];
    }
    if (tid < R * GEO_D) gs[tid / GEO_D][tid % GEO_D] = geom[(size_t)(b * NN + n0) * GEO_D + tid];
    __syncthreads();
    {
        float s = 0.0f;
#pragma unroll
        for (int k = lane; k < OBJ_D; k += 64) { float x = esT[k * 4 + wid]; s += x * x; }
        s = wave_allreduce_sum(s);
        if (lane == 0) rn[wid] = 1.0f / fmaxf(sqrtf(s), 1e-12f);
    }
    __syncthreads();
#pragma unroll
    for (int k = 0; k < 5; k++) {
        float nv = ev[k] * rn[er[k]];
        esT[ed[k] * 4 + er[k]] = nv;   // own slot
    }
    __syncthreads();

    // embT2[b][d][jpair]: pair = {emb_n[n0+2rp][d], emb_n[n0+2rp+1][d]}
    for (int idx = tid; idx < 2 * OBJ_D; idx += 256) {
        int d = idx >> 1, rp = idx & 1;
        float a = esT[d * 4 + 2 * rp];
        float c = esT[d * 4 + 2 * rp + 1];
        embT2[((size_t)(b * OBJ_D + d)) * 256 + (n0 >> 1) + rp] = __floats2half2_rn(a, c);
    }

    float ai[R] = {0, 0, 0, 0}, aj[R] = {0, 0, 0, 0};
    for (int d0 = 0; d0 < OBJ_D; d0 += 16) {
        if (d0 + 16 < OBJ_D) {
#pragma unroll
            for (int k = 0; k < 16; k++) {
                win[k] = WiC[(size_t)(d0 + 16 + k) * HID];
                wjn[k] = WjC[(size_t)(d0 + 16 + k) * HID];
            }
        }
#pragma unroll
        for (int k = 0; k < 16; k++) {
            float4 e4 = esT4[d0 + k];
            ai[0] = fmaf(e4.x, wi[k], ai[0]); aj[0] = fmaf(e4.x, wj[k], aj[0]);
            ai[1] = fmaf(e4.y, wi[k], ai[1]); aj[1] = fmaf(e4.y, wj[k], aj[1]);
            ai[2] = fmaf(e4.z, wi[k], ai[2]); aj[2] = fmaf(e4.z, wj[k], aj[2]);
            ai[3] = fmaf(e4.w, wi[k], ai[3]); aj[3] = fmaf(e4.w, wj[k], aj[3]);
        }
#pragma unroll
        for (int k = 0; k < 16; k++) { wi[k] = win[k]; wj[k] = wjn[k]; }
    }

    float gw[GEO_D];
#pragma unroll
    for (int g = 0; g < GEO_D; g++) gw[g] = W1[(size_t)(2 * OBJ_D + g) * HID + tid];
    float w2v = W2[tid];
    float vj[R];
#pragma unroll
    for (int r = 0; r < R; r++) {
        float gp = 0.0f;
#pragma unroll
        for (int g = 0; g < GEO_D; g++) gp = fmaf(gs[r][g], gw[g], gp);
        float yi = ai[r] - gp;
        vj[r] = aj[r] + gp;
        hi_p[(size_t)(b * NN + n0 + r) * HID + tid] = yi;
        Bj_h[((size_t)(b * NN + n0 + r)) * HID + tid] = (_Float16)vj[r];
    }
#pragma unroll
    for (int r = 0; r < R; r++) {
        float v = vj[r], v2 = v * v;
        float sj = fmaf(v2, fmaf(GK1, v2, GK0), 0.5f * v);   // 0.5v + GK0 v^2 + GK1 v^4
        float ds = wave_allreduce_sum(w2v * sj);
        if (lane == 0) redD[wid][r] = ds;
    }
    __syncthreads();
    if (tid < R)
        DjT[b * NN + n0 + tid] = redD[0][tid] + redD[1][tid] + redD[2][tid] + redD[3][tid];
}

// k_main: 64 blocks = (b, 16 i-rows), 512 threads (8 waves).
// Phase 0: x = hi+hl; As = SCA*W2*x (f16, LDS); CiT exact fp32.
// Phase 1: cross GEMM [16x256]@[256x512] via mfma_f32_16x16x32_f16 (B^T-input
//          pattern: both frags = 16B of consecutive-k at row/col = lane&15,
//          k-group = (lane>>4)*8). S = cross/256 + DjT.
// Phase 2: row softmax (32 threads/row), unnormalized E->f16 LDS, sum/dot fp32.
// Phase 3: context GEMM [16x512]@[512x320] (B from embT2), scale by 1/sum at store.
__global__ __launch_bounds__(512) void k_main(const float* __restrict__ hi_p,
                                              const _Float16* __restrict__ Bj_h,
                                              const __half2* __restrict__ embT2,
                                              const float* __restrict__ hl,
                                              const float* __restrict__ W2,
                                              const float* __restrict__ b2p,
                                              const float* __restrict__ DjT,
                                              float* __restrict__ out) {
    int b = blockIdx.x & 1;
    int i0 = (blockIdx.x >> 1) * 16;
    int tid = threadIdx.x;
    int l = tid & 63, w = tid >> 6;
    int ar = l & 15, ag = (l >> 4) * 8;
    int srow0 = (l >> 4) * 4;

    __shared__ alignas(16) _Float16 As[16][264];   // +8 pad: frag reads ~2-way
    __shared__ float S[16][516];                   // +4 pad
    __shared__ alignas(16) _Float16 El[16][520];   // +8 pad
    __shared__ float CiTs[16], sumL[16], dotL[16];

    // ---- phase 0 ----
    {
        int row = tid >> 5;
        int hq = (tid & 31) * 8;
        const float* hp = hi_p + ((size_t)(b * NN + i0 + row)) * HID + hq;
        const float* hlp = hl + b * HID + hq;
        const float* w2p = W2 + hq;
        float ci = 0.0f;
        v8h av;
#pragma unroll
        for (int k = 0; k < 8; k++) {
            float x = hp[k] + hlp[k];
            float w2k = w2p[k];
            av[k] = (_Float16)(x * w2k * SCA);
            float x2 = x * x;
            ci = fmaf(w2k, fmaf(x2, fmaf(GK1, x2, GK0), 0.5f * x), ci);
        }
        *(v8h*)&As[row][hq] = av;
#pragma unroll
        for (int o = 16; o > 0; o >>= 1) ci += __shfl_xor(ci, o, 64);
        if ((tid & 31) == 0) CiTs[row] = ci;
    }
    __syncthreads();

    // ---- phase 1: score cross GEMM ----
    {
        v8h afr[8];
#pragma unroll
        for (int t = 0; t < 8; t++) afr[t] = *(const v8h*)&As[ar][t * 32 + ag];
        const _Float16* Bb = Bj_h + (size_t)b * NN * HID;
        const float* Djb = DjT + b * NN;
        int jt0 = w * 4;
#pragma unroll
        for (int q = 0; q < 4; q++) {
            int j0 = (jt0 + q) * 16;
            const _Float16* bp = Bb + (size_t)(j0 + ar) * HID + ag;
            f32x4 cA = {0.0f, 0.0f, 0.0f, 0.0f}, cB = {0.0f, 0.0f, 0.0f, 0.0f};
#pragma unroll
            for (int t = 0; t < 4; t++) {
                v8h b0 = *(const v8h*)(bp + (2 * t) * 32);
                v8h b1v = *(const v8h*)(bp + (2 * t + 1) * 32);
                cA = __builtin_amdgcn_mfma_f32_16x16x32_f16(afr[2 * t], b0, cA, 0, 0, 0);
                cB = __builtin_amdgcn_mfma_f32_16x16x32_f16(afr[2 * t + 1], b1v, cB, 0, 0, 0);
            }
            f32x4 cc = cA + cB;
            float dj = Djb[j0 + ar];
#pragma unroll
            for (int r = 0; r < 4; r++)
                S[srow0 + r][j0 + ar] = cc[r] * INV_SCA + dj;
        }
    }
    __syncthreads();

    // ---- phase 2: softmax (row = tid>>5, 32 threads/row) ----
    {
        int row = tid >> 5, g = tid & 31;
        float sv[16];
#pragma unroll
        for (int jj = 0; jj < 16; jj++) sv[jj] = S[row][g + 32 * jj];
        float m = sv[0];
#pragma unroll
        for (int jj = 1; jj < 16; jj++) m = fmaxf(m, sv[jj]);
#pragma unroll
        for (int o = 16; o > 0; o >>= 1) m = fmaxf(m, __shfl_xor(m, o, 64));
        float se = 0.0f, sd = 0.0f;
#pragma unroll
        for (int jj = 0; jj < 16; jj++) {
            float e = __expf(sv[jj] - m);
            se += e;
            sd = fmaf(e, sv[jj], sd);
            El[row][g + 32 * jj] = (_Float16)e;
        }
#pragma unroll
        for (int o = 16; o > 0; o >>= 1) { se += __shfl_xor(se, o, 64); sd += __shfl_xor(sd, o, 64); }
        if (g == 0) { sumL[row] = se; dotL[row] = sd; }
    }
    __syncthreads();

    if (tid < 16) {
        float Ssum = sumL[tid];
        out[b * NN + i0 + tid] = CiTs[tid] + b2p[0] + dotL[tid] / Ssum;
        sumL[tid] = 1.0f / Ssum;   // repurpose as inv for context scaling
    }
    __syncthreads();

    // ---- phase 3: context GEMM ----
    {
        v8h ef[16];
#pragma unroll
        for (int t = 0; t < 16; t++) ef[t] = *(const v8h*)&El[ar][t * 32 + ag];
        const __half2* Eb = embT2 + (size_t)b * OBJ_D * 256;
        float* op = out + BATCH * NN + ((size_t)(b * NN + i0)) * OBJ_D;
        for (int t5 = w; t5 < 20; t5 += 8) {
            int d0 = t5 * 16;
            const __half2* bp = Eb + (size_t)(d0 + ar) * 256 + (ag >> 1);
            f32x4 cA = {0.0f, 0.0f, 0.0f, 0.0f}, cB = {0.0f, 0.0f, 0.0f, 0.0f};
#pragma unroll
            for (int kk = 0; kk < 8; kk++) {
                v8h b0 = *(const v8h*)(bp + (2 * kk) * 16);
                v8h b1v = *(const v8h*)(bp + (2 * kk + 1) * 16);
                cA = __builtin_amdgcn_mfma_f32_16x16x32_f16(ef[2 * kk], b0, cA, 0, 0, 0);
                cB = __builtin_amdgcn_mfma_f32_16x16x32_f16(ef[2 * kk + 1], b1v, cB, 0, 0, 0);
            }
            f32x4 cc = cA + cB;
#pragma unroll
            for (int r = 0; r < 4; r++) {
                int ir = srow0 + r;
                op[(size_t)ir * OBJ_D + d0 + ar] = cc[r] * sumL[ir];
            }
        }
    }
}

extern "C" void kernel_launch(void* const* d_in, const int* in_sizes, int n_in,
                              void* d_out, int out_size, void* d_ws, size_t ws_size,
                              hipStream_t stream) {
    const float* emb   = (const float*)d_in[0];
    const float* geom  = (const float*)d_in[1];
    const float* utter = (const float*)d_in[2];
    const float* W1    = (const float*)d_in[3];
    const float* b1    = (const float*)d_in[4];
    const float* W2    = (const float*)d_in[5];
    const float* b2    = (const float*)d_in[6];
    float* out = (float*)d_out;

    float* ws = (float*)d_ws;
    float* hl     = ws;                                   // 512
    float* hi_p   = ws + 512;                             // BATCH*NN*HID
    float* DjT    = hi_p + (size_t)BATCH * NN * HID;      // BATCH*NN
    _Float16* Bj_h = (_Float16*)(DjT + BATCH * NN);       // BATCH*NN*HID f16
    __half2* embT2 = (__half2*)(Bj_h + (size_t)BATCH * NN * HID); // BATCH*OBJ_D*256 half2

    hipLaunchKernelGGL(k_pre, dim3(256 + BATCH), dim3(256), 0, stream,
                       emb, geom, utter, W1, b1, W2, embT2, hi_p, Bj_h, hl, DjT);
    hipLaunchKernelGGL(k_main, dim3(BATCH * NN / 16), dim3(512), 0, stream,
                       hi_p, Bj_h, embT2, hl, W2, b2, DjT, out);
}

// Round 3
// 103.211 us; speedup vs baseline: 1.0441x; 1.0075x over previous
//
#include <hip/hip_runtime.h>
#include <hip/hip_fp16.h>
#include <math.h>

#define OBJ_D 320
#define LANG_D 256
#define GEO_D 6
#define HID 256
#define NN 512
#define BATCH 2

// gelu(a) ~= 0.5a + GK0*a^2 + GK1*a^4,  GK1 = -GK0/6.
// Factorized: score = Ci + Dj + 2*GK0*sum_h (W2*x_i)*v_j (quartic cross ~1e-8, dropped)
#define GK0 0.3989422804014327f
#define GK1 (-0.066490380066905448f)
#define SCA (512.0f * GK0)
#define INV_SCA (1.0f / 256.0f)

typedef _Float16 v8h __attribute__((ext_vector_type(8)));
typedef float f32x4 __attribute__((ext_vector_type(4)));

__device__ __forceinline__ float wave_allreduce_sum(float v) {
#pragma unroll
    for (int o = 32; o > 0; o >>= 1) v += __shfl_xor(v, o, 64);
    return v;
}

// k_pre: blocks 0..255 = fused l2norm + dual fp32 matmul for 4 rows.
// v3: matmul runs on UNNORMALIZED esT (l2norm is linear -> scale ai/aj by rn
// afterward); each wave computes all 4 row-norms redundantly so only 2
// barriers remain (esT publish, redD reduce).
// blocks 256..257 = lang norm + hl matvec (b1 folded).
__global__ __launch_bounds__(256) void k_pre(const float* __restrict__ emb,
                                             const float* __restrict__ geom,
                                             const float* __restrict__ utter,
                                             const float* __restrict__ W1,
                                             const float* __restrict__ b1,
                                             const float* __restrict__ W2,
                                             __half2* __restrict__ embT2,
                                             float* __restrict__ hi_p,
                                             _Float16* __restrict__ Bj_h,
                                             float* __restrict__ hl,
                                             float* __restrict__ DjT) {
    int tid = threadIdx.x;
    int wid = tid >> 6, lane = tid & 63;

    __shared__ float4 esT4[OBJ_D];
    __shared__ float gs[4][GEO_D];
    __shared__ float lang_s[LANG_D];
    __shared__ float red[8];
    __shared__ float redD[4][4];
    float* esT = (float*)esT4;

    if (blockIdx.x >= 256) {
        int lb = blockIdx.x - 256;
        float v = utter[lb * LANG_D + tid];
        float ss = wave_allreduce_sum(v * v);
        if (lane == 0) red[wid] = ss;
        __syncthreads();
        if (tid == 0) red[0] = 1.0f / fmaxf(sqrtf(red[0] + red[1] + red[2] + red[3]), 1e-12f);
        __syncthreads();
        lang_s[tid] = v * red[0];
        __syncthreads();
        const float* Wl = W1 + (size_t)(2 * OBJ_D + GEO_D) * HID + tid;
        float acc = b1[tid];
#pragma unroll 8
        for (int l2 = 0; l2 < LANG_D; l2++) acc = fmaf(lang_s[l2], Wl[(size_t)l2 * HID], acc);
        hl[lb * HID + tid] = acc;
        return;
    }

    const int R = 4;
    int b = blockIdx.x & 1;
    int n0 = (blockIdx.x >> 1) * R;

    // emb loads first (they feed the one barrier on the critical path)
    const float* esrc = emb + (size_t)(b * NN + n0) * OBJ_D;
    float ev[5]; int er[5], ed[5];
#pragma unroll
    for (int k = 0; k < 5; k++) {
        int idx = k * 256 + tid;
        ev[k] = esrc[idx];
        er[k] = idx / OBJ_D; ed[k] = idx % OBJ_D;
        esT[ed[k] * 4 + er[k]] = ev[k];
    }
    if (tid < R * GEO_D) gs[tid / GEO_D][tid % GEO_D] = geom[(size_t)(b * NN + n0) * GEO_D + tid];

    // W1 prefetch issues while esT settles
    const float* WiC = W1 + tid;
    const float* WjC = W1 + (size_t)OBJ_D * HID + tid;
    float wi[16], wj[16], win[16], wjn[16];
#pragma unroll
    for (int k = 0; k < 16; k++) {
        wi[k] = WiC[(size_t)k * HID];
        wj[k] = WjC[(size_t)k * HID];
    }
    __syncthreads();

    // per-wave redundant row-norms (no broadcast barrier needed)
    float rnv[4];
    {
        float sq0 = 0.0f, sq1 = 0.0f, sq2 = 0.0f, sq3 = 0.0f;
#pragma unroll
        for (int it = 0; it < 5; it++) {
            float4 e4 = esT4[lane + 64 * it];
            sq0 = fmaf(e4.x, e4.x, sq0); sq1 = fmaf(e4.y, e4.y, sq1);
            sq2 = fmaf(e4.z, e4.z, sq2); sq3 = fmaf(e4.w, e4.w, sq3);
        }
        rnv[0] = 1.0f / fmaxf(sqrtf(wave_allreduce_sum(sq0)), 1e-12f);
        rnv[1] = 1.0f / fmaxf(sqrtf(wave_allreduce_sum(sq1)), 1e-12f);
        rnv[2] = 1.0f / fmaxf(sqrtf(wave_allreduce_sum(sq2)), 1e-12f);
        rnv[3] = 1.0f / fmaxf(sqrtf(wave_allreduce_sum(sq3)), 1e-12f);
    }

    // embT2[b][d][jpair] (normalized at pack time), stores fly during matmul
    for (int idx = tid; idx < 2 * OBJ_D; idx += 256) {
        int d = idx >> 1, rp = idx & 1;
        float a = esT[d * 4 + 2 * rp] * rnv[2 * rp];
        float c = esT[d * 4 + 2 * rp + 1] * rnv[2 * rp + 1];
        embT2[((size_t)(b * OBJ_D + d)) * 256 + (n0 >> 1) + rp] = __floats2half2_rn(a, c);
    }

    // dual matmul on UNNORMALIZED esT
    float ai[R] = {0, 0, 0, 0}, aj[R] = {0, 0, 0, 0};
    for (int d0 = 0; d0 < OBJ_D; d0 += 16) {
        if (d0 + 16 < OBJ_D) {
#pragma unroll
            for (int k = 0; k < 16; k++) {
                win[k] = WiC[(size_t)(d0 + 16 + k) * HID];
                wjn[k] = WjC[(size_t)(d0 + 16 + k) * HID];
            }
        }
#pragma unroll
        for (int k = 0; k < 16; k++) {
            float4 e4 = esT4[d0 + k];
            ai[0] = fmaf(e4.x, wi[k], ai[0]); aj[0] = fmaf(e4.x, wj[k], aj[0]);
            ai[1] = fmaf(e4.y, wi[k], ai[1]); aj[1] = fmaf(e4.y, wj[k], aj[1]);
            ai[2] = fmaf(e4.z, wi[k], ai[2]); aj[2] = fmaf(e4.z, wj[k], aj[2]);
            ai[3] = fmaf(e4.w, wi[k], ai[3]); aj[3] = fmaf(e4.w, wj[k], aj[3]);
        }
#pragma unroll
        for (int k = 0; k < 16; k++) { wi[k] = win[k]; wj[k] = wjn[k]; }
    }

    float gw[GEO_D];
#pragma unroll
    for (int g = 0; g < GEO_D; g++) gw[g] = W1[(size_t)(2 * OBJ_D + g) * HID + tid];
    float w2v = W2[tid];
    float vj[R];
#pragma unroll
    for (int r = 0; r < R; r++) {
        float gp = 0.0f;
#pragma unroll
        for (int g = 0; g < GEO_D; g++) gp = fmaf(gs[r][g], gw[g], gp);
        float yi = ai[r] * rnv[r] - gp;
        vj[r] = aj[r] * rnv[r] + gp;
        hi_p[(size_t)(b * NN + n0 + r) * HID + tid] = yi;
        Bj_h[((size_t)(b * NN + n0 + r)) * HID + tid] = (_Float16)vj[r];
    }
#pragma unroll
    for (int r = 0; r < R; r++) {
        float v = vj[r], v2 = v * v;
        float sj = fmaf(v2, fmaf(GK1, v2, GK0), 0.5f * v);
        float ds = wave_allreduce_sum(w2v * sj);
        if (lane == 0) redD[wid][r] = ds;
    }
    __syncthreads();
    if (tid < R)
        DjT[b * NN + n0 + tid] = redD[0][tid] + redD[1][tid] + redD[2][tid] + redD[3][tid];
}

__device__ __forceinline__ void load_tile8(v8h* dst, const _Float16* bp) {
#pragma unroll
    for (int t = 0; t < 8; t++) dst[t] = *(const v8h*)(bp + t * 32);
}

__device__ __forceinline__ void score_tile(const v8h* afr, const v8h* bt,
                                           float (*S)[516], int srow0, int col, float dj) {
    f32x4 cA = {0.0f, 0.0f, 0.0f, 0.0f}, cB = {0.0f, 0.0f, 0.0f, 0.0f};
#pragma unroll
    for (int t = 0; t < 4; t++) {
        cA = __builtin_amdgcn_mfma_f32_16x16x32_f16(afr[2 * t], bt[2 * t], cA, 0, 0, 0);
        cB = __builtin_amdgcn_mfma_f32_16x16x32_f16(afr[2 * t + 1], bt[2 * t + 1], cB, 0, 0, 0);
    }
    f32x4 cc = cA + cB;
#pragma unroll
    for (int r = 0; r < 4; r++) S[srow0 + r][col] = cc[r] * INV_SCA + dj;
}

// k_main v3: 64 blocks = (b, 16 i-rows), 512 threads (8 waves).
// Round-1 verified numerics + cross-barrier prefetch (loads issued before a
// __syncthreads complete AT it) + 2-deep bA/bB pipeline in phase 1 + one
// barrier removed in phase 2/3 handoff (per-thread redundant 1/sum).
__global__ __launch_bounds__(512, 2) void k_main(const float* __restrict__ hi_p,
                                                 const _Float16* __restrict__ Bj_h,
                                                 const __half2* __restrict__ embT2,
                                                 const float* __restrict__ hl,
                                                 const float* __restrict__ W2,
                                                 const float* __restrict__ b2p,
                                                 const float* __restrict__ DjT,
                                                 float* __restrict__ out) {
    int b = blockIdx.x & 1;
    int i0 = (blockIdx.x >> 1) * 16;
    int tid = threadIdx.x;
    int lane = tid & 63, w = tid >> 6;
    int ar = lane & 15, ag = (lane >> 4) * 8;
    int srow0 = (lane >> 4) * 4;

    __shared__ alignas(16) _Float16 As[16][264];
    __shared__ float S[16][516];
    __shared__ alignas(16) _Float16 El[16][520];
    __shared__ float CiTs[16], sumL[16], dotL[16];

    const _Float16* Bb = Bj_h + (size_t)b * NN * HID;
    const float* Djb = DjT + b * NN;
    int jt0 = w * 4;

    // pre-barrier prefetch: q=0 B-tile + all Dj (independent of As)
    v8h bA[8], bB[8];
    float dj[4];
    load_tile8(bA, Bb + (size_t)(jt0 * 16 + ar) * HID + ag);
#pragma unroll
    for (int q = 0; q < 4; q++) dj[q] = Djb[(jt0 + q) * 16 + ar];

    // ---- phase 0: As = SCA*W2*(hi+hl) f16; Ci exact fp32 ----
    {
        int row = tid >> 5;
        int hq = (tid & 31) * 8;
        const float* hp = hi_p + ((size_t)(b * NN + i0 + row)) * HID + hq;
        const float* hlp = hl + b * HID + hq;
        const float* w2p = W2 + hq;
        float ci = 0.0f;
        v8h av;
#pragma unroll
        for (int k = 0; k < 8; k++) {
            float x = hp[k] + hlp[k];
            float w2k = w2p[k];
            av[k] = (_Float16)(x * w2k * SCA);
            float x2 = x * x;
            ci = fmaf(w2k, fmaf(x2, fmaf(GK1, x2, GK0), 0.5f * x), ci);
        }
        *(v8h*)&As[row][hq] = av;
#pragma unroll
        for (int o = 16; o > 0; o >>= 1) ci += __shfl_xor(ci, o, 64);
        if ((tid & 31) == 0) CiTs[row] = ci;
    }
    __syncthreads();

    // ---- phase 1: score cross GEMM, 2-deep pipeline ----
    {
        v8h afr[8];
#pragma unroll
        for (int t = 0; t < 8; t++) afr[t] = *(const v8h*)&As[ar][t * 32 + ag];
        load_tile8(bB, Bb + (size_t)((jt0 + 1) * 16 + ar) * HID + ag);
        score_tile(afr, bA, S, srow0, jt0 * 16 + ar, dj[0]);
        load_tile8(bA, Bb + (size_t)((jt0 + 2) * 16 + ar) * HID + ag);
        score_tile(afr, bB, S, srow0, (jt0 + 1) * 16 + ar, dj[1]);
        load_tile8(bB, Bb + (size_t)((jt0 + 3) * 16 + ar) * HID + ag);
        score_tile(afr, bA, S, srow0, (jt0 + 2) * 16 + ar, dj[2]);
        score_tile(afr, bB, S, srow0, (jt0 + 3) * 16 + ar, dj[3]);
    }
    __syncthreads();

    // phase-3 first-tile prefetch: flies under the softmax VALU work,
    // drained by the phase-2 closing barrier.
    const __half2* Eb = embT2 + (size_t)b * OBJ_D * 256;
    v8h eT[16];
    {
        const __half2* bp = Eb + (size_t)(w * 16 + ar) * 256 + (ag >> 1);
#pragma unroll
        for (int t = 0; t < 16; t++) eT[t] = *(const v8h*)(bp + t * 16);
    }

    // ---- phase 2: softmax (row = tid>>5, 32 threads/row) ----
    {
        int row = tid >> 5, g = tid & 31;
        float sv[16];
#pragma unroll
        for (int jj = 0; jj < 16; jj++) sv[jj] = S[row][g + 32 * jj];
        float m = sv[0];
#pragma unroll
        for (int jj = 1; jj < 16; jj++) m = fmaxf(m, sv[jj]);
#pragma unroll
        for (int o = 16; o > 0; o >>= 1) m = fmaxf(m, __shfl_xor(m, o, 64));
        float se = 0.0f, sd = 0.0f;
#pragma unroll
        for (int jj = 0; jj < 16; jj++) {
            float e = __expf(sv[jj] - m);
            se += e;
            sd = fmaf(e, sv[jj], sd);
            El[row][g + 32 * jj] = (_Float16)e;
        }
#pragma unroll
        for (int o = 16; o > 0; o >>= 1) { se += __shfl_xor(se, o, 64); sd += __shfl_xor(sd, o, 64); }
        if (g == 0) { sumL[row] = se; dotL[row] = sd; }
    }
    __syncthreads();

    if (tid < 16)
        out[b * NN + i0 + tid] = CiTs[tid] + b2p[0] + dotL[tid] / sumL[tid];

    // ---- phase 3: context GEMM (per-thread redundant 1/sum, no extra barrier) ----
    {
        float iv[4];
#pragma unroll
        for (int r = 0; r < 4; r++) iv[r] = 1.0f / sumL[srow0 + r];
        v8h ef[16];
#pragma unroll
        for (int t = 0; t < 16; t++) ef[t] = *(const v8h*)&El[ar][t * 32 + ag];
        float* op = out + BATCH * NN + ((size_t)(b * NN + i0)) * OBJ_D;
        for (int t5 = w; t5 < 20; t5 += 8) {
            int d0 = t5 * 16;
            if (t5 != w) {
                const __half2* bp = Eb + (size_t)(d0 + ar) * 256 + (ag >> 1);
#pragma unroll
                for (int t = 0; t < 16; t++) eT[t] = *(const v8h*)(bp + t * 16);
            }
            f32x4 cA = {0.0f, 0.0f, 0.0f, 0.0f}, cB = {0.0f, 0.0f, 0.0f, 0.0f};
#pragma unroll
            for (int t = 0; t < 8; t++) {
                cA = __builtin_amdgcn_mfma_f32_16x16x32_f16(ef[2 * t], eT[2 * t], cA, 0, 0, 0);
                cB = __builtin_amdgcn_mfma_f32_16x16x32_f16(ef[2 * t + 1], eT[2 * t + 1], cB, 0, 0, 0);
            }
            f32x4 cc = cA + cB;
#pragma unroll
            for (int r = 0; r < 4; r++)
                op[(size_t)(srow0 + r) * OBJ_D + d0 + ar] = cc[r] * iv[r];
        }
    }
}

extern "C" void kernel_launch(void* const* d_in, const int* in_sizes, int n_in,
                              void* d_out, int out_size, void* d_ws, size_t ws_size,
                              hipStream_t stream) {
    const float* emb   = (const float*)d_in[0];
    const float* geom  = (const float*)d_in[1];
    const float* utter = (const float*)d_in[2];
    const float* W1    = (const float*)d_in[3];
    const float* b1    = (const float*)d_in[4];
    const float* W2    = (const float*)d_in[5];
    const float* b2    = (const float*)d_in[6];
    float* out = (float*)d_out;

    float* ws = (float*)d_ws;
    float* hl      = ws;                                    // 512
    float* hi_p    = ws + 512;                              // BATCH*NN*HID
    float* DjT     = hi_p + (size_t)BATCH * NN * HID;       // BATCH*NN
    _Float16* Bj_h = (_Float16*)(DjT + BATCH * NN);         // BATCH*NN*HID f16
    __half2* embT2 = (__half2*)(Bj_h + (size_t)BATCH * NN * HID); // BATCH*OBJ_D*256 half2

    hipLaunchKernelGGL(k_pre, dim3(256 + BATCH), dim3(256), 0, stream,
                       emb, geom, utter, W1, b1, W2, embT2, hi_p, Bj_h, hl, DjT);
    hipLaunchKernelGGL(k_main, dim3(BATCH * NN / 16), dim3(512), 0, stream,
                       hi_p, Bj_h, embT2, hl, W2, b2, DjT, out);
}

// Round 4
// 100.920 us; speedup vs baseline: 1.0678x; 1.0227x over previous
//
#include <hip/hip_runtime.h>
#include <hip/hip_fp16.h>
#include <math.h>

#define OBJ_D 320
#define LANG_D 256
#define GEO_D 6
#define HID 256
#define NN 512
#define BATCH 2

// gelu(a) ~= 0.5a + GK0*a^2 + GK1*a^4,  GK1 = -GK0/6.
// Factorized: score = Ci + Dj + 2*GK0*sum_h (W2*x_i)*v_j (quartic cross ~1e-8, dropped)
#define GK0 0.3989422804014327f
#define GK1 (-0.066490380066905448f)
#define SCA (512.0f * GK0)
#define INV_SCA (1.0f / 256.0f)

typedef _Float16 v8h __attribute__((ext_vector_type(8)));
typedef float f32x4 __attribute__((ext_vector_type(4)));

__device__ __forceinline__ float wave_allreduce_sum(float v) {
#pragma unroll
    for (int o = 32; o > 0; o >>= 1) v += __shfl_xor(v, o, 64);
    return v;
}

// k_pre v4 (column-split): blocks 0..255 = (row-group g = bid>>2 : 16 rows,
// H-quarter q = bid&3 : h in [64q, 64q+64)). Each block reads only 1/4 of the
// Wi/Wj panel -> W1 L2 traffic 168 MB -> 42 MB. Wave w owns rows 4w..4w+3
// (norms via wave-local allreduce; Dj partials straight to DjP[q][j]).
// One barrier total. Matmul on UNNORMALIZED esT, post-scaled by rnv (linear).
// blocks 256..257 = lang norm + hl matvec (b1 folded).
__global__ __launch_bounds__(256) void k_pre(const float* __restrict__ emb,
                                             const float* __restrict__ geom,
                                             const float* __restrict__ utter,
                                             const float* __restrict__ W1,
                                             const float* __restrict__ b1,
                                             const float* __restrict__ W2,
                                             __half2* __restrict__ embT2,
                                             float* __restrict__ hi_p,
                                             _Float16* __restrict__ Bj_h,
                                             float* __restrict__ hl,
                                             float* __restrict__ DjP) {
    int tid = threadIdx.x;
    int wid = tid >> 6, lane = tid & 63;

    __shared__ alignas(16) float esT[OBJ_D * 20];   // [d][16 rows + pad4]; f4 @ d*20+4*rg
    __shared__ float gs[16][GEO_D];
    __shared__ float lang_s[LANG_D];
    __shared__ float red[8];

    if (blockIdx.x >= 256) {
        int lb = blockIdx.x - 256;
        float v = utter[lb * LANG_D + tid];
        float ss = wave_allreduce_sum(v * v);
        if (lane == 0) red[wid] = ss;
        __syncthreads();
        if (tid == 0) red[0] = 1.0f / fmaxf(sqrtf(red[0] + red[1] + red[2] + red[3]), 1e-12f);
        __syncthreads();
        lang_s[tid] = v * red[0];
        __syncthreads();
        const float* Wl = W1 + (size_t)(2 * OBJ_D + GEO_D) * HID + tid;
        float acc = b1[tid];
#pragma unroll 8
        for (int l2 = 0; l2 < LANG_D; l2++) acc = fmaf(lang_s[l2], Wl[(size_t)l2 * HID], acc);
        hl[lb * HID + tid] = acc;
        return;
    }

    int q = blockIdx.x & 3;
    int g = blockIdx.x >> 2;
    int b = g & 1;
    int n0 = (g >> 1) * 16;
    int h = q * 64 + lane;     // this thread's H column
    int rg = wid;              // wave owns rows 4*rg .. 4*rg+3

    // stage emb 16 rows x 320 -> esT[d][r] (transposed, +4 pad for f4 alignment)
    const float* esrc = emb + (size_t)(b * NN + n0) * OBJ_D;
#pragma unroll
    for (int it = 0; it < 20; it++) {
        int idx = it * 256 + tid;              // 0..5119
        int r = idx / OBJ_D, d = idx - r * OBJ_D;
        esT[d * 20 + r] = esrc[idx];
    }
    if (tid < 16 * GEO_D) gs[tid / GEO_D][tid % GEO_D] = geom[(size_t)(b * NN + n0) * GEO_D + tid];

    // W prefetch (first 16 dims) issues while esT settles; drained at the barrier
    const float* WiC = W1 + h;
    const float* WjC = W1 + (size_t)OBJ_D * HID + h;
    float wi[16], wj[16], win[16], wjn[16];
#pragma unroll
    for (int k = 0; k < 16; k++) {
        wi[k] = WiC[(size_t)k * HID];
        wj[k] = WjC[(size_t)k * HID];
    }
    __syncthreads();

    // per-wave norms for its 4 rows (wave-local; no broadcast barrier)
    float rnv[4];
    {
        float sq0 = 0.0f, sq1 = 0.0f, sq2 = 0.0f, sq3 = 0.0f;
#pragma unroll
        for (int it = 0; it < 5; it++) {
            float4 e4 = *(const float4*)&esT[(lane + 64 * it) * 20 + 4 * rg];
            sq0 = fmaf(e4.x, e4.x, sq0); sq1 = fmaf(e4.y, e4.y, sq1);
            sq2 = fmaf(e4.z, e4.z, sq2); sq3 = fmaf(e4.w, e4.w, sq3);
        }
        rnv[0] = 1.0f / fmaxf(sqrtf(wave_allreduce_sum(sq0)), 1e-12f);
        rnv[1] = 1.0f / fmaxf(sqrtf(wave_allreduce_sum(sq1)), 1e-12f);
        rnv[2] = 1.0f / fmaxf(sqrtf(wave_allreduce_sum(sq2)), 1e-12f);
        rnv[3] = 1.0f / fmaxf(sqrtf(wave_allreduce_sum(sq3)), 1e-12f);
    }

    // embT2[b][d][jpair] from q==0 blocks only; wave w writes its own 2 pairs
    // (rows 2rg.. via wave-local rnv -> no rnS, no barrier). Stores fly during matmul.
    if (q == 0) {
#pragma unroll
        for (int it = 0; it < 10; it++) {
            int idx = it * 64 + lane;          // 0..639
            int d = idx >> 1, pp = idx & 1;    // pp: which of this wave's 2 pairs
            int rp = 2 * rg + pp;
            float ra = pp ? rnv[2] : rnv[0];
            float rc = pp ? rnv[3] : rnv[1];
            float a = esT[d * 20 + 2 * rp] * ra;
            float c = esT[d * 20 + 2 * rp + 1] * rc;
            embT2[((size_t)(b * OBJ_D + d)) * 256 + (n0 >> 1) + rp] = __floats2half2_rn(a, c);
        }
    }

    // dual matmul on UNNORMALIZED esT (rows 4rg..4rg+3, this thread's h col)
    float ai[4] = {0, 0, 0, 0}, aj[4] = {0, 0, 0, 0};
    for (int d0 = 0; d0 < OBJ_D; d0 += 16) {
        if (d0 + 16 < OBJ_D) {
#pragma unroll
            for (int k = 0; k < 16; k++) {
                win[k] = WiC[(size_t)(d0 + 16 + k) * HID];
                wjn[k] = WjC[(size_t)(d0 + 16 + k) * HID];
            }
        }
#pragma unroll
        for (int k = 0; k < 16; k++) {
            float4 e4 = *(const float4*)&esT[(d0 + k) * 20 + 4 * rg];   // wave-uniform: broadcast
            ai[0] = fmaf(e4.x, wi[k], ai[0]); aj[0] = fmaf(e4.x, wj[k], aj[0]);
            ai[1] = fmaf(e4.y, wi[k], ai[1]); aj[1] = fmaf(e4.y, wj[k], aj[1]);
            ai[2] = fmaf(e4.z, wi[k], ai[2]); aj[2] = fmaf(e4.z, wj[k], aj[2]);
            ai[3] = fmaf(e4.w, wi[k], ai[3]); aj[3] = fmaf(e4.w, wj[k], aj[3]);
        }
#pragma unroll
        for (int k = 0; k < 16; k++) { wi[k] = win[k]; wj[k] = wjn[k]; }
    }

    float gw[GEO_D];
#pragma unroll
    for (int gg = 0; gg < GEO_D; gg++) gw[gg] = W1[(size_t)(2 * OBJ_D + gg) * HID + h];
    float w2v = W2[h];
#pragma unroll
    for (int r = 0; r < 4; r++) {
        int row = 4 * rg + r;
        float gp = 0.0f;
#pragma unroll
        for (int gg = 0; gg < GEO_D; gg++) gp = fmaf(gs[row][gg], gw[gg], gp);
        float yi = ai[r] * rnv[r] - gp;
        float vjv = aj[r] * rnv[r] + gp;
        hi_p[(size_t)(b * NN + n0 + row) * HID + h] = yi;
        Bj_h[((size_t)(b * NN + n0 + row)) * HID + h] = (_Float16)vjv;
        float v2 = vjv * vjv;
        float sj = fmaf(v2, fmaf(GK1, v2, GK0), 0.5f * vjv);
        float ds = wave_allreduce_sum(w2v * sj);   // partial over this block's 64 h
        if (lane == 0) DjP[q * (BATCH * NN) + b * NN + n0 + row] = ds;
    }
}

__device__ __forceinline__ void load_tile8(v8h* dst, const _Float16* bp) {
#pragma unroll
    for (int t = 0; t < 8; t++) dst[t] = *(const v8h*)(bp + t * 32);
}

__device__ __forceinline__ void score_tile(const v8h* afr, const v8h* bt,
                                           float (*S)[516], int srow0, int col, float dj) {
    f32x4 cA = {0.0f, 0.0f, 0.0f, 0.0f}, cB = {0.0f, 0.0f, 0.0f, 0.0f};
#pragma unroll
    for (int t = 0; t < 4; t++) {
        cA = __builtin_amdgcn_mfma_f32_16x16x32_f16(afr[2 * t], bt[2 * t], cA, 0, 0, 0);
        cB = __builtin_amdgcn_mfma_f32_16x16x32_f16(afr[2 * t + 1], bt[2 * t + 1], cB, 0, 0, 0);
    }
    f32x4 cc = cA + cB;
#pragma unroll
    for (int r = 0; r < 4; r++) S[srow0 + r][col] = cc[r] * INV_SCA + dj;
}

// k_main v4: identical to verified v3 except Dj = sum of 4 DjP partials
// (loaded in the already-overlapped pre-barrier prefetch).
__global__ __launch_bounds__(512, 2) void k_main(const float* __restrict__ hi_p,
                                                 const _Float16* __restrict__ Bj_h,
                                                 const __half2* __restrict__ embT2,
                                                 const float* __restrict__ hl,
                                                 const float* __restrict__ W2,
                                                 const float* __restrict__ b2p,
                                                 const float* __restrict__ DjP,
                                                 float* __restrict__ out) {
    int b = blockIdx.x & 1;
    int i0 = (blockIdx.x >> 1) * 16;
    int tid = threadIdx.x;
    int lane = tid & 63, w = tid >> 6;
    int ar = lane & 15, ag = (lane >> 4) * 8;
    int srow0 = (lane >> 4) * 4;

    __shared__ alignas(16) _Float16 As[16][264];
    __shared__ float S[16][516];
    __shared__ alignas(16) _Float16 El[16][520];
    __shared__ float CiTs[16], sumL[16], dotL[16];

    const _Float16* Bb = Bj_h + (size_t)b * NN * HID;
    const float* Djb = DjP + b * NN;
    int jt0 = w * 4;

    // pre-barrier prefetch: q=0 B-tile + all Dj partials (independent of As)
    v8h bA[8], bB[8];
    float dj[4];
    load_tile8(bA, Bb + (size_t)(jt0 * 16 + ar) * HID + ag);
#pragma unroll
    for (int qq = 0; qq < 4; qq++) {
        int jj = (jt0 + qq) * 16 + ar;
        dj[qq] = (Djb[jj] + Djb[jj + BATCH * NN]) +
                 (Djb[jj + 2 * BATCH * NN] + Djb[jj + 3 * BATCH * NN]);
    }

    // ---- phase 0: As = SCA*W2*(hi+hl) f16; Ci exact fp32 ----
    {
        int row = tid >> 5;
        int hq = (tid & 31) * 8;
        const float* hp = hi_p + ((size_t)(b * NN + i0 + row)) * HID + hq;
        const float* hlp = hl + b * HID + hq;
        const float* w2p = W2 + hq;
        float ci = 0.0f;
        v8h av;
#pragma unroll
        for (int k = 0; k < 8; k++) {
            float x = hp[k] + hlp[k];
            float w2k = w2p[k];
            av[k] = (_Float16)(x * w2k * SCA);
            float x2 = x * x;
            ci = fmaf(w2k, fmaf(x2, fmaf(GK1, x2, GK0), 0.5f * x), ci);
        }
        *(v8h*)&As[row][hq] = av;
#pragma unroll
        for (int o = 16; o > 0; o >>= 1) ci += __shfl_xor(ci, o, 64);
        if ((tid & 31) == 0) CiTs[row] = ci;
    }
    __syncthreads();

    // ---- phase 1: score cross GEMM, 2-deep pipeline ----
    {
        v8h afr[8];
#pragma unroll
        for (int t = 0; t < 8; t++) afr[t] = *(const v8h*)&As[ar][t * 32 + ag];
        load_tile8(bB, Bb + (size_t)((jt0 + 1) * 16 + ar) * HID + ag);
        score_tile(afr, bA, S, srow0, jt0 * 16 + ar, dj[0]);
        load_tile8(bA, Bb + (size_t)((jt0 + 2) * 16 + ar) * HID + ag);
        score_tile(afr, bB, S, srow0, (jt0 + 1) * 16 + ar, dj[1]);
        load_tile8(bB, Bb + (size_t)((jt0 + 3) * 16 + ar) * HID + ag);
        score_tile(afr, bA, S, srow0, (jt0 + 2) * 16 + ar, dj[2]);
        score_tile(afr, bB, S, srow0, (jt0 + 3) * 16 + ar, dj[3]);
    }
    __syncthreads();

    // phase-3 first-tile prefetch: flies under the softmax VALU work
    const __half2* Eb = embT2 + (size_t)b * OBJ_D * 256;
    v8h eT[16];
    {
        const __half2* bp = Eb + (size_t)(w * 16 + ar) * 256 + (ag >> 1);
#pragma unroll
        for (int t = 0; t < 16; t++) eT[t] = *(const v8h*)(bp + t * 16);
    }

    // ---- phase 2: softmax (row = tid>>5, 32 threads/row) ----
    {
        int row = tid >> 5, gg = tid & 31;
        float sv[16];
#pragma unroll
        for (int jj = 0; jj < 16; jj++) sv[jj] = S[row][gg + 32 * jj];
        float m = sv[0];
#pragma unroll
        for (int jj = 1; jj < 16; jj++) m = fmaxf(m, sv[jj]);
#pragma unroll
        for (int o = 16; o > 0; o >>= 1) m = fmaxf(m, __shfl_xor(m, o, 64));
        float se = 0.0f, sd = 0.0f;
#pragma unroll
        for (int jj = 0; jj < 16; jj++) {
            float e = __expf(sv[jj] - m);
            se += e;
            sd = fmaf(e, sv[jj], sd);
            El[row][gg + 32 * jj] = (_Float16)e;
        }
#pragma unroll
        for (int o = 16; o > 0; o >>= 1) { se += __shfl_xor(se, o, 64); sd += __shfl_xor(sd, o, 64); }
        if (gg == 0) { sumL[row] = se; dotL[row] = sd; }
    }
    __syncthreads();

    if (tid < 16)
        out[b * NN + i0 + tid] = CiTs[tid] + b2p[0] + dotL[tid] / sumL[tid];

    // ---- phase 3: context GEMM (per-thread redundant 1/sum, no extra barrier) ----
    {
        float iv[4];
#pragma unroll
        for (int r = 0; r < 4; r++) iv[r] = 1.0f / sumL[srow0 + r];
        v8h ef[16];
#pragma unroll
        for (int t = 0; t < 16; t++) ef[t] = *(const v8h*)&El[ar][t * 32 + ag];
        float* op = out + BATCH * NN + ((size_t)(b * NN + i0)) * OBJ_D;
        for (int t5 = w; t5 < 20; t5 += 8) {
            int d0 = t5 * 16;
            if (t5 != w) {
                const __half2* bp = Eb + (size_t)(d0 + ar) * 256 + (ag >> 1);
#pragma unroll
                for (int t = 0; t < 16; t++) eT[t] = *(const v8h*)(bp + t * 16);
            }
            f32x4 cA = {0.0f, 0.0f, 0.0f, 0.0f}, cB = {0.0f, 0.0f, 0.0f, 0.0f};
#pragma unroll
            for (int t = 0; t < 8; t++) {
                cA = __builtin_amdgcn_mfma_f32_16x16x32_f16(ef[2 * t], eT[2 * t], cA, 0, 0, 0);
                cB = __builtin_amdgcn_mfma_f32_16x16x32_f16(ef[2 * t + 1], eT[2 * t + 1], cB, 0, 0, 0);
            }
            f32x4 cc = cA + cB;
#pragma unroll
            for (int r = 0; r < 4; r++)
                op[(size_t)(srow0 + r) * OBJ_D + d0 + ar] = cc[r] * iv[r];
        }
    }
}

extern "C" void kernel_launch(void* const* d_in, const int* in_sizes, int n_in,
                              void* d_out, int out_size, void* d_ws, size_t ws_size,
                              hipStream_t stream) {
    const float* emb   = (const float*)d_in[0];
    const float* geom  = (const float*)d_in[1];
    const float* utter = (const float*)d_in[2];
    const float* W1    = (const float*)d_in[3];
    const float* b1    = (const float*)d_in[4];
    const float* W2    = (const float*)d_in[5];
    const float* b2    = (const float*)d_in[6];
    float* out = (float*)d_out;

    float* ws = (float*)d_ws;
    float* hl      = ws;                                    // 512
    float* hi_p    = ws + 512;                              // BATCH*NN*HID
    float* DjP     = hi_p + (size_t)BATCH * NN * HID;       // 4*BATCH*NN
    _Float16* Bj_h = (_Float16*)(DjP + 4 * BATCH * NN);     // BATCH*NN*HID f16
    __half2* embT2 = (__half2*)(Bj_h + (size_t)BATCH * NN * HID); // BATCH*OBJ_D*256 half2

    hipLaunchKernelGGL(k_pre, dim3(256 + BATCH), dim3(256), 0, stream,
                       emb, geom, utter, W1, b1, W2, embT2, hi_p, Bj_h, hl, DjP);
    hipLaunchKernelGGL(k_main, dim3(BATCH * NN / 16), dim3(512), 0, stream,
                       hi_p, Bj_h, embT2, hl, W2, b2, DjP, out);
}